// Round 7
// baseline (45.068 us; speedup 1.0000x reference)
//
#include <hip/hip_runtime.h>
#include <cmath>

typedef unsigned short u16;
typedef __bf16 bf16x8 __attribute__((ext_vector_type(8)));
typedef float f32x4 __attribute__((ext_vector_type(4)));
typedef unsigned short u16x4 __attribute__((ext_vector_type(4)));

#define BATCH 16384
#define NTREE 32
#define NINT 63
#define NLEAF 64
#define FDIM 256
#define MT 128     // batch rows per block
#define THALF 16   // trees per block (grid.y = 2)
#define NSTEP 16   // 8 tree-pairs x 2 K-halves

typedef __attribute__((address_space(3))) void lvoid;
typedef __attribute__((address_space(1))) const void gvoid;
__device__ __forceinline__ void gload16(const void* g, void* l) {
    // DMA 16B/lane global->LDS; LDS dest = wave-uniform base + lane*16 (HW rule)
    __builtin_amdgcn_global_load_lds((gvoid*)g, (lvoid*)l, 16, 0, 0);
}

__device__ __forceinline__ u16 f2bf(float f) {
    unsigned int x = __float_as_uint(f);
    x += 0x7fffu + ((x >> 16) & 1u);   // round-to-nearest-even
    return (u16)(x >> 16);
}

// D-row slot s (0..63) -> heap node id (R6-verified permutation).
__device__ __forceinline__ int slot2node(int slot) {
    int lg = (slot >> 2) & 3;
    int v = ((slot >> 4) << 2) | (slot & 3);
    if (v == 0)  return (lg & 1) ? (1 + (lg >> 1)) : 0;
    if (v == 1)  return 3 + lg;
    if (v < 4)   return 7 + 2 * lg + (v - 2);
    if (v < 8)   return 15 + 4 * lg + (v - 4);
    return 31 + 8 * lg + (v - 8);
}

__global__ void convert_kernel(const float* __restrict__ x, const float* __restrict__ W,
                               const float* __restrict__ b,
                               u16* __restrict__ xb, u16* __restrict__ Wb,
                               float* __restrict__ bperm) {
    int idx = blockIdx.x * blockDim.x + threadIdx.x;
    int stride = gridDim.x * blockDim.x;
    const int NXQ = BATCH * FDIM / 4;
    for (int i = idx; i < NXQ; i += stride) {
        float4 v = ((const float4*)x)[i];
        u16x4 o = { f2bf(v.x), f2bf(v.y), f2bf(v.z), f2bf(v.w) };
        ((u16x4*)xb)[i] = o;
    }
    // Wb: [tree][64 slots (permuted nodes, root duplicated)][256 features]
    const int NWQ = NTREE * NLEAF * FDIM / 4;
    for (int i = idx; i < NWQ; i += stride) {
        int t = i / (NLEAF * FDIM / 4);
        int r = i % (NLEAF * FDIM / 4);
        int slot = r / (FDIM / 4);
        int kq = r % (FDIM / 4);
        int node = slot2node(slot);
        float4 v = ((const float4*)(W + ((size_t)t * NINT + node) * FDIM))[kq];
        u16x4 o = { f2bf(v.x), f2bf(v.y), f2bf(v.z), f2bf(v.w) };
        ((u16x4*)Wb)[i] = o;
    }
    if (idx < NTREE * NLEAF)
        bperm[idx] = b[(idx >> 6) * NINT + slot2node(idx & 63)];
}

// Block: 256 thr = 4 waves (rg=wv>>1 row-half, tp=wv&1 tree-slot), 128 rows x 16 trees.
// x-tile (128x256, 64KB) staged ONCE into LDS; W streamed per tree-pair in half-K
// (128 rows x 128 k = 32KB) tiles, double-buffered, one barrier/step, DMA for step
// s+1 issued AFTER the barrier (prefetch never hit by the barrier's vmcnt drain).
// Wave = 64 rows x 64 slots (4x4 frags, acc 64 VGPR). Swizzle: chunk^(row&7) within
// 8-chunk groups on BOTH the DMA global source and the ds_read side (rule 21).
// Epilogue: R6-verified register-only tree eval, accumulated over 8 trees -> 1 store.
__global__ __launch_bounds__(256) void softgbm_main(
    const u16* __restrict__ xb, const u16* __restrict__ Wb,
    const float* __restrict__ bperm, const float* __restrict__ phig,
    float* __restrict__ partial) {
    __shared__ u16 X[MT * FDIM];      // 64 KB, resident whole kernel
    __shared__ u16 Wt[2][MT * 128];   // 2 x 32 KB, double-buffered W half-K tiles

    const int tid = threadIdx.x;
    const int lane = tid & 63, wv = tid >> 6;
    const int rg = wv >> 1, tp = wv & 1;
    const int ttop = blockIdx.y * THALF;
    const int m0 = blockIdx.x * MT;
    const int frow = lane & 15, lg = lane >> 4, f7 = frow & 7;

    // ---- stage x-tile (once): 4096 chunks, 16 issues/thread, pre-swizzled source
    #pragma unroll
    for (int i = 0; i < 16; ++i) {
        int cl = i * 256 + wv * 64 + lane;
        int row = cl >> 5, pcc = cl & 31;
        int cc = (pcc & 24) | ((pcc & 7) ^ (row & 7));
        gload16(xb + (size_t)(m0 + row) * FDIM + cc * 8, &X[cl * 8]);
    }
    // ---- W staging source offsets (static per thread across steps)
    int wrowcc[8], wdst[8];
    #pragma unroll
    for (int j = 0; j < 8; ++j) {
        int cl = j * 256 + wv * 64 + lane;
        int row = cl >> 4, pcc = cl & 15;
        int cc = (pcc & 8) | ((pcc & 7) ^ (row & 7));
        wrowcc[j] = row * FDIM + cc * 8;    // u16 offset within the pair's W rows
        wdst[j] = cl * 8;
    }
    const u16* wpairbase = Wb + (size_t)ttop * NLEAF * FDIM;
    // stage step 0 (pair 0, k-half 0) into buffer 0
    #pragma unroll
    for (int j = 0; j < 8; ++j)
        gload16(wpairbase + wrowcc[j], &Wt[0][wdst[j]]);

    // ---- frag read bases (bytes) + swizzled k-offsets
    int Abase[4], Bbase[4], aoff[4], xoff[2][4];
    #pragma unroll
    for (int ar = 0; ar < 4; ++ar) Abase[ar] = (tp * 64 + ar * 16 + frow) * 256;
    #pragma unroll
    for (int bc = 0; bc < 4; ++bc) Bbase[bc] = (rg * 64 + bc * 16 + frow) * 512;
    #pragma unroll
    for (int ks = 0; ks < 4; ++ks) {
        int c = ks * 4 + lg;
        aoff[ks] = ((c & 8) | ((c & 7) ^ f7)) * 16;
        #pragma unroll
        for (int kh = 0; kh < 2; ++kh) {
            int cx = kh * 16 + ks * 4 + lg;
            xoff[kh][ks] = ((cx & 24) | ((cx & 7) ^ f7)) * 16;
        }
    }

    float rsum = 0.f;
    for (int pair = 0; pair < 8; ++pair) {
        const int t = ttop + pair * 2 + tp;
        // per-tree tables: issued early, consumed ~1300 cyc later in the epilogue
        float bl[16];
        #pragma unroll
        for (int v2 = 0; v2 < 16; ++v2)
            bl[v2] = bperm[t * 64 + (v2 >> 2) * 16 + lg * 4 + (v2 & 3)];
        float pha[8], phd[8];
        #pragma unroll
        for (int i = 0; i < 8; ++i) {
            float2 p2 = *(const float2*)&phig[(size_t)t * NLEAF + lg * 16 + 2 * i];
            pha[i] = p2.x; phd[i] = p2.y - p2.x;
        }

        f32x4 acc[4][4] = {};
        #pragma unroll
        for (int kh = 0; kh < 2; ++kh) {
            const int step = pair * 2 + kh;
            __syncthreads();               // cur buffer's DMA (issued last step) done;
                                           // all waves done reading the other buffer
            if (step + 1 < NSTEP) {        // prefetch next step AFTER the barrier
                int np = (step + 1) >> 1, nk = (step + 1) & 1;
                const u16* ws = wpairbase + (size_t)np * 128 * FDIM + nk * 128;
                u16* wd = Wt[(step + 1) & 1];
                #pragma unroll
                for (int j = 0; j < 8; ++j)
                    gload16(ws + wrowcc[j], &wd[wdst[j]]);
            }
            const char* Wc = (const char*)Wt[step & 1];
            const char* Xc = (const char*)X;
            #pragma unroll
            for (int ks = 0; ks < 4; ++ks) {
                bf16x8 af[4], bf_[4];
                #pragma unroll
                for (int ar = 0; ar < 4; ++ar)
                    af[ar] = *(const bf16x8*)(Wc + Abase[ar] + aoff[ks]);
                #pragma unroll
                for (int bc = 0; bc < 4; ++bc)
                    bf_[bc] = *(const bf16x8*)(Xc + Bbase[bc] + xoff[kh][ks]);
                #pragma unroll
                for (int ar = 0; ar < 4; ++ar)
                    #pragma unroll
                    for (int bc = 0; bc < 4; ++bc)
                        acc[ar][bc] = __builtin_amdgcn_mfma_f32_16x16x32_bf16(af[ar], bf_[bc], acc[ar][bc], 0, 0, 0);
            }
        }

        // ---- in-register tree eval (R6-verified), overlaps next pair's DMA
        float tot[4];
        #pragma unroll
        for (int bc = 0; bc < 4; ++bc) {
            float pv[16];
            #pragma unroll
            for (int v2 = 0; v2 < 16; ++v2) {
                float z = acc[v2 >> 2][bc][v2 & 3] + bl[v2];
                pv[v2] = __builtin_amdgcn_rcpf(1.f + __expf(-z));
            }
            float o = __shfl_xor(pv[0], 16);
            float proot = (lg & 1) ? o : pv[0];
            float pd1   = (lg & 1) ? pv[0] : o;
            float mb = ((lg >> 1) ? proot : 1.f - proot) * ((lg & 1) ? pd1 : 1.f - pd1);
            float m3[2], m4[4], m5[8];
            { float t1 = mb * pv[1]; m3[1] = t1; m3[0] = mb - t1; }
            #pragma unroll
            for (int i = 0; i < 2; ++i) { float t1 = m3[i] * pv[2 + i]; m4[2*i+1] = t1; m4[2*i] = m3[i] - t1; }
            #pragma unroll
            for (int i = 0; i < 4; ++i) { float t1 = m4[i] * pv[4 + i]; m5[2*i+1] = t1; m5[2*i] = m4[i] - t1; }
            float s = 0.f;
            #pragma unroll
            for (int i = 0; i < 8; ++i) s += m5[i] * (pha[i] + pv[8 + i] * phd[i]);
            s += __shfl_xor(s, 16);
            s += __shfl_xor(s, 32);
            tot[bc] = s;
        }
        float vout = (lg & 2) ? ((lg & 1) ? tot[3] : tot[2])
                              : ((lg & 1) ? tot[1] : tot[0]);
        rsum += vout;
    }
    // lane = lg*16+frow holds row rg*64+lane's sum over this wave's 8 trees
    partial[(size_t)(blockIdx.y * 2 + tp) * BATCH + m0 + rg * 64 + lane] = rsum;
}

__global__ void reduce_kernel(const float* __restrict__ partial, float* __restrict__ out) {
    int i = blockIdx.x * 256 + threadIdx.x;
    float s = partial[i] + partial[BATCH + i] + partial[2 * BATCH + i] + partial[3 * BATCH + i];
    out[i] = 0.1f * s;
}

extern "C" void kernel_launch(void* const* d_in, const int* in_sizes, int n_in,
                              void* d_out, int out_size, void* d_ws, size_t ws_size,
                              hipStream_t stream) {
    const float* x   = (const float*)d_in[0];
    const float* W   = (const float*)d_in[1];
    const float* b   = (const float*)d_in[2];
    const float* phi = (const float*)d_in[3];
    float* out = (float*)d_out;

    u16* xb = (u16*)d_ws;                                  // 16384*256 bf16 = 8 MB
    u16* Wb = xb + (size_t)BATCH * FDIM;                   // 32*64*256 bf16 = 1 MB
    float* partial = (float*)(Wb + (size_t)NTREE * NLEAF * FDIM);  // 4*16384 f32 = 256 KB
    float* bperm = partial + (size_t)4 * BATCH;            // 32*64 f32 = 8 KB

    convert_kernel<<<2048, 256, 0, stream>>>(x, W, b, xb, Wb, bperm);
    softgbm_main<<<dim3(BATCH / MT, 2), 256, 0, stream>>>(xb, Wb, bperm, phi, partial);
    reduce_kernel<<<BATCH / 256, 256, 0, stream>>>(partial, out);
}